// Round 13
// baseline (75.822 us; speedup 1.0000x reference)
//
#include <hip/hip_runtime.h>
#include <math.h>

constexpr int NN = 100000;   // nodes
constexpr int NE = 1250000;  // edges
constexpr int NF = 64;       // input features
constexpr int NH = 16;       // hidden
constexpr int NC = 7;        // classes

constexpr int BKT_SHIFT = 7;                 // 128 nodes per bucket
constexpr int BKT_NODES = 1 << BKT_SHIFT;    // 128
constexpr int NBUCKET = (NN + BKT_NODES - 1) / BKT_NODES;  // 782
constexpr int BSTRIDE = 2048;                // capacity per bucket (mean 1598)
constexpr int EPB = 4096;                    // edges per scatter block
constexpr int NBLK_BUCKET = (NE + EPB - 1) / EPB;          // 306
constexpr int NBLK_PAD = 320;                // padded row for gcnt/gbase
constexpr int EPC = 4096;                    // edges per count block (fused)
constexpr int NBLK_COUNT = (NE + EPC - 1) / EPC;           // 306
constexpr int NODE_BLOCKS = (NN + 255) / 256;              // 391

// ---- wave-level inclusive scan (64 lanes) ----
__device__ __forceinline__ int wave_iscan(int v, int lane) {
#pragma unroll
    for (int d = 1; d < 64; d <<= 1) {
        int u = __shfl_up(v, d, 64);
        if (lane >= d) v += u;
    }
    return v;
}

// ------- Fused: blocks [0,NODE_BLOCKS) do A = x@W1 ; rest do dst histogram -------
__global__ __launch_bounds__(256) void k1_fused(
    const float* __restrict__ x, const float* __restrict__ W1,
    float* __restrict__ A, const int* __restrict__ dst, int* __restrict__ gcnt) {
    if (blockIdx.x >= NODE_BLOCKS) {
        __shared__ int cnt[NBUCKET];
        int blk = blockIdx.x - NODE_BLOCKS;
        int tid = threadIdx.x;
        for (int i = tid; i < NBUCKET; i += 256) cnt[i] = 0;
        __syncthreads();
        int base = blk * EPC;
#pragma unroll
        for (int k = 0; k < EPC / 256; ++k) {
            int e = base + k * 256 + tid;
            if (e < NE) atomicAdd(&cnt[dst[e] >> BKT_SHIFT], 1);   // LDS int atomic
        }
        __syncthreads();
        for (int i = tid; i < NBUCKET; i += 256)
            gcnt[i * NBLK_PAD + blk] = cnt[i];
        return;
    }
    // ---- GEMM part ----
    __shared__ float w[NF * NH];   // 4 KB
    for (int i = threadIdx.x; i < NF * NH; i += 256) w[i] = W1[i];
    __syncthreads();
    int node = blockIdx.x * 256 + threadIdx.x;
    if (node >= NN) return;

    float acc[NH];
#pragma unroll
    for (int j = 0; j < NH; ++j) acc[j] = 0.f;

    const float4* xr = (const float4*)(x + (size_t)node * NF);
#pragma unroll
    for (int k4 = 0; k4 < NF / 4; ++k4) {
        float4 xv = xr[k4];
        int k = k4 * 4;
#pragma unroll
        for (int j = 0; j < NH; ++j) {
            acc[j] += xv.x * w[(k + 0) * NH + j]
                    + xv.y * w[(k + 1) * NH + j]
                    + xv.z * w[(k + 2) * NH + j]
                    + xv.w * w[(k + 3) * NH + j];
        }
    }
    float4* Ar = (float4*)(A + (size_t)node * NH);
#pragma unroll
    for (int q = 0; q < NH / 4; ++q) {
        float4 a;
        a.x = acc[q * 4 + 0]; a.y = acc[q * 4 + 1];
        a.z = acc[q * 4 + 2]; a.w = acc[q * 4 + 3];
        Ar[q] = a;
    }
}

// ------- Phase B: per-bucket exclusive scan over block counts (wave scan) -------
__global__ __launch_bounds__(320) void k_base(
    const int* __restrict__ gcnt, int* __restrict__ gbase, int* __restrict__ tcnt) {
    __shared__ int wsum[5];
    int b = blockIdx.x;
    int tid = threadIdx.x;
    int lane = tid & 63, wid = tid >> 6;
    int v = (tid < NBLK_COUNT) ? gcnt[b * NBLK_PAD + tid] : 0;
    int sv = wave_iscan(v, lane);
    if (lane == 63) wsum[wid] = sv;
    __syncthreads();
    if (wid == 0) {
        int wv = (lane < 5) ? wsum[lane] : 0;
        int ws = wave_iscan(wv, lane);
        if (lane < 5) wsum[lane] = ws - wv;   // exclusive
    }
    __syncthreads();
    int excl = sv - v + wsum[wid];
    if (tid < NBLK_COUNT) gbase[b * NBLK_PAD + tid] = excl;
    if (tid == NBLK_COUNT - 1) tcnt[b] = excl + v;
}

// ------- Phase C: LDS counting sort by bucket, write to precomputed slots -------
__global__ __launch_bounds__(1024) void k_scatter(
    const int* __restrict__ src, const int* __restrict__ dst,
    const int* __restrict__ gbase, unsigned* __restrict__ gbuf) {
    __shared__ int cnt[NBUCKET];
    __shared__ int loff[NBUCKET];
    __shared__ int gb[NBUCKET];
    __shared__ int wsum[16];
    __shared__ unsigned sorted[EPB];        // 16 KB
    __shared__ unsigned short sortedB[EPB]; // 8 KB

    int tid = threadIdx.x;
    for (int i = tid; i < NBUCKET; i += 1024) {
        cnt[i] = 0;
        gb[i] = gbase[i * NBLK_PAD + blockIdx.x];
    }
    __syncthreads();

    unsigned pk[EPB / 1024];
    int bk[EPB / 1024];
    int rk[EPB / 1024];
    int base = blockIdx.x * EPB;
    int nval = NE - base; if (nval > EPB) nval = EPB;
#pragma unroll
    for (int k = 0; k < EPB / 1024; ++k) {
        int e = base + k * 1024 + tid;
        bk[k] = -1;
        if (e < NE) {
            int sv = src[e];
            int d = dst[e];
            int b = d >> BKT_SHIFT;
            bk[k] = b;
            pk[k] = ((unsigned)sv << BKT_SHIFT) | (unsigned)(d & (BKT_NODES - 1));
            rk[k] = atomicAdd(&cnt[b], 1);   // LDS int atomic (native)
        }
    }
    __syncthreads();

    int lane = tid & 63, wid = tid >> 6;
    int v = (tid < NBUCKET) ? cnt[tid] : 0;
    int sv = wave_iscan(v, lane);
    if (lane == 63) wsum[wid] = sv;
    __syncthreads();
    if (wid == 0) {
        int wv = (lane < 16) ? wsum[lane] : 0;
        int ws = wave_iscan(wv, lane);
        if (lane < 16) wsum[lane] = ws - wv;
    }
    __syncthreads();
    if (tid < NBUCKET) loff[tid] = sv - v + wsum[wid];
    __syncthreads();

#pragma unroll
    for (int k = 0; k < EPB / 1024; ++k) {
        if (bk[k] >= 0) {
            int p = loff[bk[k]] + rk[k];
            sorted[p] = pk[k];
            sortedB[p] = (unsigned short)bk[k];
        }
    }
    __syncthreads();

    for (int i = tid; i < nval; i += 1024) {
        int b = sortedB[i];
        int pos = gb[b] + (i - loff[b]);
        if (pos < BSTRIDE)   // statistically impossible overflow guard
            gbuf[(size_t)b * BSTRIDE + pos] = sorted[i];
    }
}

// ------- k_agg1: counting-sort by local dst, degree-balanced unroll-4 gather,
//         FUSED mid MLP. Persists sorted src list + (start,cnt) for k_agg2. -------
__global__ __launch_bounds__(512) void k_agg1(
    const float* __restrict__ A, float* __restrict__ A2,
    const int* __restrict__ tcnt, unsigned* __restrict__ gbuf,
    unsigned short* __restrict__ soff, unsigned short* __restrict__ scnt,
    const float* __restrict__ b1,
    const float* __restrict__ W2, const float* __restrict__ b2,
    const float* __restrict__ W3) {
    __shared__ unsigned stage[BSTRIDE];   // 8 KB
    __shared__ unsigned eSrc[BSTRIDE];    // 8 KB
    __shared__ int cnt[BKT_NODES], off[BKT_NODES], cur[BKT_NODES];
    __shared__ int perm[BKT_NODES];       // degree-sorted node order
    __shared__ int wtot[2];
    __shared__ float Bl[BKT_NODES * 17];
    __shared__ float Tl[BKT_NODES * 17];
    __shared__ float w2[NH * NH], w3[NH * NH], bb1[NH], bb2[NH];

    int b = blockIdx.x;
    int tid = threadIdx.x;
    for (int i = tid; i < NH * NH; i += 512) { w2[i] = W2[i]; w3[i] = W3[i]; }
    if (tid < NH) { bb1[tid] = b1[tid]; bb2[tid] = b2[tid]; }
    int n = tcnt[b];
    if (n > BSTRIDE) n = BSTRIDE;
    if (tid < BKT_NODES) cnt[tid] = 0;
    __syncthreads();

    for (int i = tid; i < n; i += 512) {
        unsigned u = gbuf[(size_t)b * BSTRIDE + i];
        stage[i] = u;
        atomicAdd(&cnt[u & (BKT_NODES - 1)], 1);
    }
    __syncthreads();

    // 128-entry inclusive scan via 2 wave scans
    int lane = tid & 63, wid = tid >> 6;
    int sv = 0, v = 0;
    if (tid < BKT_NODES) {
        v = cnt[tid];
        sv = wave_iscan(v, lane);
        if (lane == 63) wtot[wid] = sv;
    }
    __syncthreads();
    if (tid < BKT_NODES) {
        int add = (wid == 1) ? wtot[0] : 0;
        int inc = sv + add;
        off[tid] = inc;
        int st = inc - v;
        cur[tid] = st;
        soff[b * BKT_NODES + tid] = (unsigned short)st;
        scnt[b * BKT_NODES + tid] = (unsigned short)v;
        // degree-rank permutation: rank by descending cnt (ties by index)
        int r = 0;
        for (int j = 0; j < BKT_NODES; ++j) {
            int cj = cnt[j];
            r += (cj > v) || (cj == v && j < tid);
        }
        perm[r] = tid;
    }
    __syncthreads();
    for (int i = tid; i < n; i += 512) {
        unsigned u = stage[i];
        int pos = atomicAdd(&cur[u & (BKT_NODES - 1)], 1);
        eSrc[pos] = u >> BKT_SHIFT;
    }
    __syncthreads();

    // persist sorted src list for k_agg2
    for (int i = tid; i < n; i += 512) gbuf[(size_t)b * BSTRIDE + i] = eSrc[i];

    // gather: degree-balanced — 4 lanes per node, nodes in degree order
    int nd = perm[tid >> 2];
    int q = (tid & 3) * 4;
    int gnd = (b << BKT_SHIFT) + nd;
    int end = off[nd];
    int start = end - cnt[nd];

    float4 bq = {0.f, 0.f, 0.f, 0.f};
    if (gnd < NN) bq = *(const float4*)(A + (size_t)gnd * NH + q);
    float4 a0 = {0.f, 0.f, 0.f, 0.f}, a1 = {0.f, 0.f, 0.f, 0.f};
    float4 a2 = {0.f, 0.f, 0.f, 0.f}, a3 = {0.f, 0.f, 0.f, 0.f};
    int j = start;
    for (; j + 4 <= end; j += 4) {
        int e0 = eSrc[j];
        int e1 = eSrc[j + 1];
        int e2 = eSrc[j + 2];
        int e3 = eSrc[j + 3];
        float4 v0 = *(const float4*)(A + (size_t)e0 * NH + q);
        float4 v1 = *(const float4*)(A + (size_t)e1 * NH + q);
        float4 v2 = *(const float4*)(A + (size_t)e2 * NH + q);
        float4 v3 = *(const float4*)(A + (size_t)e3 * NH + q);
        a0.x += v0.x; a0.y += v0.y; a0.z += v0.z; a0.w += v0.w;
        a1.x += v1.x; a1.y += v1.y; a1.z += v1.z; a1.w += v1.w;
        a2.x += v2.x; a2.y += v2.y; a2.z += v2.z; a2.w += v2.w;
        a3.x += v3.x; a3.y += v3.y; a3.z += v3.z; a3.w += v3.w;
    }
    for (; j < end; ++j) {
        int e0 = eSrc[j];
        float4 v0 = *(const float4*)(A + (size_t)e0 * NH + q);
        a0.x += v0.x; a0.y += v0.y; a0.z += v0.z; a0.w += v0.w;
    }
    a0.x += a2.x; a0.y += a2.y; a0.z += a2.z; a0.w += a2.w;
    a1.x += a3.x; a1.y += a3.y; a1.z += a3.z; a1.w += a3.w;
    Bl[nd * 17 + q + 0] = fmaxf(bq.x + bb1[q + 0] + a0.x + a1.x, 0.f);
    Bl[nd * 17 + q + 1] = fmaxf(bq.y + bb1[q + 1] + a0.y + a1.y, 0.f);
    Bl[nd * 17 + q + 2] = fmaxf(bq.z + bb1[q + 2] + a0.z + a1.z, 0.f);
    Bl[nd * 17 + q + 3] = fmaxf(bq.w + bb1[q + 3] + a0.w + a1.w, 0.f);
    __syncthreads();

    // t = relu(h@W2+b2)  (unpermuted node order)
    int node = tid >> 2;
    int gnode = (b << BKT_SHIFT) + node;
    float t0 = bb2[q], t1 = bb2[q + 1], t2 = bb2[q + 2], t3 = bb2[q + 3];
#pragma unroll
    for (int k = 0; k < NH; ++k) {
        float hk = Bl[node * 17 + k];
        t0 += hk * w2[k * NH + q + 0];
        t1 += hk * w2[k * NH + q + 1];
        t2 += hk * w2[k * NH + q + 2];
        t3 += hk * w2[k * NH + q + 3];
    }
    Tl[node * 17 + q + 0] = fmaxf(t0, 0.f);
    Tl[node * 17 + q + 1] = fmaxf(t1, 0.f);
    Tl[node * 17 + q + 2] = fmaxf(t2, 0.f);
    Tl[node * 17 + q + 3] = fmaxf(t3, 0.f);
    __syncthreads();

    // z = t@W3 ; A2 = z  (b3 folded into agg2's self-term)
    float z0 = 0.f, z1 = 0.f, z2 = 0.f, z3 = 0.f;
#pragma unroll
    for (int k = 0; k < NH; ++k) {
        float tk = Tl[node * 17 + k];
        z0 += tk * w3[k * NH + q + 0];
        z1 += tk * w3[k * NH + q + 1];
        z2 += tk * w3[k * NH + q + 2];
        z3 += tk * w3[k * NH + q + 3];
    }
    if (gnode < NN) {
        float4 az = {z0, z1, z2, z3};
        *(float4*)(A2 + (size_t)gnode * NH + q) = az;
    }
}

// ------- k_agg2: NO sort (persisted list); degree-balanced gather; fused head. -------
__global__ __launch_bounds__(512) void k_agg2(
    const float* __restrict__ A2,
    const int* __restrict__ tcnt, const unsigned* __restrict__ gbuf,
    const unsigned short* __restrict__ soff, const unsigned short* __restrict__ scnt,
    const float* __restrict__ b3,
    const float* __restrict__ W4, const float* __restrict__ b4,
    float* __restrict__ out) {
    __shared__ unsigned eSrc[BSTRIDE];
    __shared__ int off[BKT_NODES], cnt[BKT_NODES];
    __shared__ int perm[BKT_NODES];
    __shared__ float Bl[BKT_NODES * 17];
    __shared__ float w4[NH * NC];
    __shared__ float bb3[NH];
    __shared__ float bb4[NC];

    int b = blockIdx.x;
    int tid = threadIdx.x;
    for (int i = tid; i < NH * NC; i += 512) w4[i] = W4[i];
    if (tid < NH) bb3[tid] = b3[tid];
    if (tid < NC) bb4[tid] = b4[tid];
    int n = tcnt[b];
    if (n > BSTRIDE) n = BSTRIDE;
    if (tid < BKT_NODES) {
        off[tid] = soff[b * BKT_NODES + tid];
        cnt[tid] = scnt[b * BKT_NODES + tid];
    }
    for (int i = tid; i < n; i += 512) eSrc[i] = gbuf[(size_t)b * BSTRIDE + i];
    __syncthreads();

    if (tid < BKT_NODES) {
        int v = cnt[tid];
        int r = 0;
        for (int j = 0; j < BKT_NODES; ++j) {
            int cj = cnt[j];
            r += (cj > v) || (cj == v && j < tid);
        }
        perm[r] = tid;
    }
    __syncthreads();

    int nd = perm[tid >> 2];
    int q = (tid & 3) * 4;
    int gnd = (b << BKT_SHIFT) + nd;
    int start = off[nd] - cnt[nd] + cnt[nd];   // off holds start already
    start = off[nd];
    int end = start + cnt[nd];

    float4 bq = {0.f, 0.f, 0.f, 0.f};
    if (gnd < NN) bq = *(const float4*)(A2 + (size_t)gnd * NH + q);
    float4 a0 = {0.f, 0.f, 0.f, 0.f}, a1 = {0.f, 0.f, 0.f, 0.f};
    float4 a2 = {0.f, 0.f, 0.f, 0.f}, a3 = {0.f, 0.f, 0.f, 0.f};
    int j = start;
    for (; j + 4 <= end; j += 4) {
        int e0 = eSrc[j];
        int e1 = eSrc[j + 1];
        int e2 = eSrc[j + 2];
        int e3 = eSrc[j + 3];
        float4 v0 = *(const float4*)(A2 + (size_t)e0 * NH + q);
        float4 v1 = *(const float4*)(A2 + (size_t)e1 * NH + q);
        float4 v2 = *(const float4*)(A2 + (size_t)e2 * NH + q);
        float4 v3 = *(const float4*)(A2 + (size_t)e3 * NH + q);
        a0.x += v0.x; a0.y += v0.y; a0.z += v0.z; a0.w += v0.w;
        a1.x += v1.x; a1.y += v1.y; a1.z += v1.z; a1.w += v1.w;
        a2.x += v2.x; a2.y += v2.y; a2.z += v2.z; a2.w += v2.w;
        a3.x += v3.x; a3.y += v3.y; a3.z += v3.z; a3.w += v3.w;
    }
    for (; j < end; ++j) {
        int e0 = eSrc[j];
        float4 v0 = *(const float4*)(A2 + (size_t)e0 * NH + q);
        a0.x += v0.x; a0.y += v0.y; a0.z += v0.z; a0.w += v0.w;
    }
    a0.x += a2.x; a0.y += a2.y; a0.z += a2.z; a0.w += a2.w;
    a1.x += a3.x; a1.y += a3.y; a1.z += a3.z; a1.w += a3.w;
    Bl[nd * 17 + q + 0] = fmaxf(bq.x + bb3[q + 0] + a0.x + a1.x, 0.f);
    Bl[nd * 17 + q + 1] = fmaxf(bq.y + bb3[q + 1] + a0.y + a1.y, 0.f);
    Bl[nd * 17 + q + 2] = fmaxf(bq.z + bb3[q + 2] + a0.z + a1.z, 0.f);
    Bl[nd * 17 + q + 3] = fmaxf(bq.w + bb3[q + 3] + a0.w + a1.w, 0.f);
    __syncthreads();

    // head: one thread per node
    if (tid < BKT_NODES) {
        int ndh = tid;
        int gn = (b << BKT_SHIFT) + ndh;
        if (gn < NN) {
            float o[NC];
#pragma unroll
            for (int c = 0; c < NC; ++c) o[c] = bb4[c];
#pragma unroll
            for (int k = 0; k < NH; ++k) {
                float hk = Bl[ndh * 17 + k];
#pragma unroll
                for (int c = 0; c < NC; ++c) o[c] += hk * w4[k * NC + c];
            }
            float m = o[0];
#pragma unroll
            for (int c = 1; c < NC; ++c) m = fmaxf(m, o[c]);
            float s = 0.f;
#pragma unroll
            for (int c = 0; c < NC; ++c) s += expf(o[c] - m);
            float ls = m + logf(s);
            float* op = out + (size_t)gn * NC;
#pragma unroll
            for (int c = 0; c < NC; ++c) op[c] = o[c] - ls;
        }
    }
}

extern "C" void kernel_launch(void* const* d_in, const int* in_sizes, int n_in,
                              void* d_out, int out_size, void* d_ws, size_t ws_size,
                              hipStream_t stream) {
    const float* x  = (const float*)d_in[0];
    const int*   ei = (const int*)d_in[1];   // [2, NE] flat: src then dst
    const float* W1 = (const float*)d_in[2];
    const float* b1 = (const float*)d_in[3];
    const float* W2 = (const float*)d_in[4];
    const float* b2 = (const float*)d_in[5];
    const float* W3 = (const float*)d_in[6];
    const float* b3 = (const float*)d_in[7];
    const float* W4 = (const float*)d_in[8];
    const float* b4 = (const float*)d_in[9];
    float* out = (float*)d_out;

    const int* src = ei;
    const int* dst = ei + NE;

    // workspace layout
    float*          A    = (float*)d_ws;                           // 6.4 MB
    float*          A2   = A + (size_t)NN * NH;                    // 6.4 MB
    unsigned*       gbuf = (unsigned*)(A2 + (size_t)NN * NH);      // 6.4 MB
    int*            gcnt = (int*)(gbuf + (size_t)NBUCKET * BSTRIDE);   // 1 MB
    int*            gbase= gcnt + (size_t)NBUCKET * NBLK_PAD;      // 1 MB
    int*            tcnt = gbase + (size_t)NBUCKET * NBLK_PAD;     // 3 KB
    unsigned short* soff = (unsigned short*)(tcnt + ((NBUCKET + 3) & ~3)); // 200 KB
    unsigned short* scnt = soff + (size_t)NBUCKET * BKT_NODES;     // 200 KB

    k1_fused<<<NODE_BLOCKS + NBLK_COUNT, 256, 0, stream>>>(x, W1, A, dst, gcnt);
    k_base<<<NBUCKET, 320, 0, stream>>>(gcnt, gbase, tcnt);
    k_scatter<<<NBLK_BUCKET, 1024, 0, stream>>>(src, dst, gbase, gbuf);
    k_agg1<<<NBUCKET, 512, 0, stream>>>(A, A2, tcnt, gbuf, soff, scnt, b1, W2, b2, W3);
    k_agg2<<<NBUCKET, 512, 0, stream>>>(A2, tcnt, gbuf, soff, scnt, b3, W4, b4, out);
}

// Round 14
// 72.604 us; speedup vs baseline: 1.0443x; 1.0443x over previous
//
#include <hip/hip_runtime.h>
#include <math.h>

constexpr int NN = 100000;   // nodes
constexpr int NE = 1250000;  // edges
constexpr int NF = 64;       // input features
constexpr int NH = 16;       // hidden
constexpr int NC = 7;        // classes

constexpr int BKT_SHIFT = 7;                 // 128 nodes per bucket
constexpr int BKT_NODES = 1 << BKT_SHIFT;    // 128
constexpr int NBUCKET = (NN + BKT_NODES - 1) / BKT_NODES;  // 782
constexpr int BSTRIDE = 2048;                // capacity per bucket (mean 1598)
constexpr int EPB = 4096;                    // edges per scatter block
constexpr int NBLK_BUCKET = (NE + EPB - 1) / EPB;          // 306
constexpr int NBLK_PAD = 320;                // padded row for gcnt/gbase
constexpr int EPC = 4096;                    // edges per count block (fused)
constexpr int NBLK_COUNT = (NE + EPC - 1) / EPC;           // 306
constexpr int NODE_BLOCKS = (NN + 255) / 256;              // 391

// ---- wave-level inclusive scan (64 lanes) ----
__device__ __forceinline__ int wave_iscan(int v, int lane) {
#pragma unroll
    for (int d = 1; d < 64; d <<= 1) {
        int u = __shfl_up(v, d, 64);
        if (lane >= d) v += u;
    }
    return v;
}

// ------- Fused: blocks [0,NODE_BLOCKS) do A = x@W1 ; rest do dst histogram -------
__global__ __launch_bounds__(256) void k1_fused(
    const float* __restrict__ x, const float* __restrict__ W1,
    float* __restrict__ A, const int* __restrict__ dst, int* __restrict__ gcnt) {
    if (blockIdx.x >= NODE_BLOCKS) {
        __shared__ int cnt[NBUCKET];
        int blk = blockIdx.x - NODE_BLOCKS;
        int tid = threadIdx.x;
        for (int i = tid; i < NBUCKET; i += 256) cnt[i] = 0;
        __syncthreads();
        int base = blk * EPC;
#pragma unroll
        for (int k = 0; k < EPC / 256; ++k) {
            int e = base + k * 256 + tid;
            if (e < NE) atomicAdd(&cnt[dst[e] >> BKT_SHIFT], 1);   // LDS int atomic
        }
        __syncthreads();
        for (int i = tid; i < NBUCKET; i += 256)
            gcnt[i * NBLK_PAD + blk] = cnt[i];
        return;
    }
    // ---- GEMM part ----
    __shared__ float w[NF * NH];   // 4 KB
    for (int i = threadIdx.x; i < NF * NH; i += 256) w[i] = W1[i];
    __syncthreads();
    int node = blockIdx.x * 256 + threadIdx.x;
    if (node >= NN) return;

    float acc[NH];
#pragma unroll
    for (int j = 0; j < NH; ++j) acc[j] = 0.f;

    const float4* xr = (const float4*)(x + (size_t)node * NF);
#pragma unroll
    for (int k4 = 0; k4 < NF / 4; ++k4) {
        float4 xv = xr[k4];
        int k = k4 * 4;
#pragma unroll
        for (int j = 0; j < NH; ++j) {
            acc[j] += xv.x * w[(k + 0) * NH + j]
                    + xv.y * w[(k + 1) * NH + j]
                    + xv.z * w[(k + 2) * NH + j]
                    + xv.w * w[(k + 3) * NH + j];
        }
    }
    float4* Ar = (float4*)(A + (size_t)node * NH);
#pragma unroll
    for (int q = 0; q < NH / 4; ++q) {
        float4 a;
        a.x = acc[q * 4 + 0]; a.y = acc[q * 4 + 1];
        a.z = acc[q * 4 + 2]; a.w = acc[q * 4 + 3];
        Ar[q] = a;
    }
}

// ------- Phase B: per-bucket exclusive scan over block counts (wave scan) -------
__global__ __launch_bounds__(320) void k_base(
    const int* __restrict__ gcnt, int* __restrict__ gbase, int* __restrict__ tcnt) {
    __shared__ int wsum[5];
    int b = blockIdx.x;
    int tid = threadIdx.x;
    int lane = tid & 63, wid = tid >> 6;
    int v = (tid < NBLK_COUNT) ? gcnt[b * NBLK_PAD + tid] : 0;
    int sv = wave_iscan(v, lane);
    if (lane == 63) wsum[wid] = sv;
    __syncthreads();
    if (wid == 0) {
        int wv = (lane < 5) ? wsum[lane] : 0;
        int ws = wave_iscan(wv, lane);
        if (lane < 5) wsum[lane] = ws - wv;   // exclusive
    }
    __syncthreads();
    int excl = sv - v + wsum[wid];
    if (tid < NBLK_COUNT) gbase[b * NBLK_PAD + tid] = excl;
    if (tid == NBLK_COUNT - 1) tcnt[b] = excl + v;
}

// ------- Phase C: LDS counting sort by bucket, write to precomputed slots -------
__global__ __launch_bounds__(1024) void k_scatter(
    const int* __restrict__ src, const int* __restrict__ dst,
    const int* __restrict__ gbase, unsigned* __restrict__ gbuf) {
    __shared__ int cnt[NBUCKET];
    __shared__ int loff[NBUCKET];
    __shared__ int gb[NBUCKET];
    __shared__ int wsum[16];
    __shared__ unsigned sorted[EPB];        // 16 KB
    __shared__ unsigned short sortedB[EPB]; // 8 KB

    int tid = threadIdx.x;
    for (int i = tid; i < NBUCKET; i += 1024) {
        cnt[i] = 0;
        gb[i] = gbase[i * NBLK_PAD + blockIdx.x];
    }
    __syncthreads();

    unsigned pk[EPB / 1024];
    int bk[EPB / 1024];
    int rk[EPB / 1024];
    int base = blockIdx.x * EPB;
    int nval = NE - base; if (nval > EPB) nval = EPB;
#pragma unroll
    for (int k = 0; k < EPB / 1024; ++k) {
        int e = base + k * 1024 + tid;
        bk[k] = -1;
        if (e < NE) {
            int sv = src[e];
            int d = dst[e];
            int b = d >> BKT_SHIFT;
            bk[k] = b;
            pk[k] = ((unsigned)sv << BKT_SHIFT) | (unsigned)(d & (BKT_NODES - 1));
            rk[k] = atomicAdd(&cnt[b], 1);   // LDS int atomic (native)
        }
    }
    __syncthreads();

    int lane = tid & 63, wid = tid >> 6;
    int v = (tid < NBUCKET) ? cnt[tid] : 0;
    int sv = wave_iscan(v, lane);
    if (lane == 63) wsum[wid] = sv;
    __syncthreads();
    if (wid == 0) {
        int wv = (lane < 16) ? wsum[lane] : 0;
        int ws = wave_iscan(wv, lane);
        if (lane < 16) wsum[lane] = ws - wv;
    }
    __syncthreads();
    if (tid < NBUCKET) loff[tid] = sv - v + wsum[wid];
    __syncthreads();

#pragma unroll
    for (int k = 0; k < EPB / 1024; ++k) {
        if (bk[k] >= 0) {
            int p = loff[bk[k]] + rk[k];
            sorted[p] = pk[k];
            sortedB[p] = (unsigned short)bk[k];
        }
    }
    __syncthreads();

    for (int i = tid; i < nval; i += 1024) {
        int b = sortedB[i];
        int pos = gb[b] + (i - loff[b]);
        if (pos < BSTRIDE)   // statistically impossible overflow guard
            gbuf[(size_t)b * BSTRIDE + pos] = sorted[i];
    }
}

// ------- k_agg1: counting-sort by local dst, unroll-4 register gather,
//         FUSED mid MLP. Persists sorted src list + (start,cnt) for k_agg2. -------
__global__ __launch_bounds__(512) void k_agg1(
    const float* __restrict__ A, float* __restrict__ A2,
    const int* __restrict__ tcnt, unsigned* __restrict__ gbuf,
    unsigned short* __restrict__ soff, unsigned short* __restrict__ scnt,
    const float* __restrict__ b1,
    const float* __restrict__ W2, const float* __restrict__ b2,
    const float* __restrict__ W3) {
    __shared__ unsigned stage[BSTRIDE];   // 8 KB
    __shared__ unsigned eSrc[BSTRIDE];    // 8 KB
    __shared__ int cnt[BKT_NODES], off[BKT_NODES], cur[BKT_NODES];
    __shared__ int wtot[2];
    __shared__ float Bl[BKT_NODES * 17];
    __shared__ float Tl[BKT_NODES * 17];
    __shared__ float w2[NH * NH], w3[NH * NH], bb1[NH], bb2[NH];

    int b = blockIdx.x;
    int tid = threadIdx.x;
    for (int i = tid; i < NH * NH; i += 512) { w2[i] = W2[i]; w3[i] = W3[i]; }
    if (tid < NH) { bb1[tid] = b1[tid]; bb2[tid] = b2[tid]; }
    int n = tcnt[b];
    if (n > BSTRIDE) n = BSTRIDE;
    if (tid < BKT_NODES) cnt[tid] = 0;
    __syncthreads();

    for (int i = tid; i < n; i += 512) {
        unsigned u = gbuf[(size_t)b * BSTRIDE + i];
        stage[i] = u;
        atomicAdd(&cnt[u & (BKT_NODES - 1)], 1);
    }
    __syncthreads();

    // 128-entry inclusive scan via 2 wave scans
    int lane = tid & 63, wid = tid >> 6;
    int sv = 0, v = 0;
    if (tid < BKT_NODES) {
        v = cnt[tid];
        sv = wave_iscan(v, lane);
        if (lane == 63) wtot[wid] = sv;
    }
    __syncthreads();
    if (tid < BKT_NODES) {
        int add = (wid == 1) ? wtot[0] : 0;
        int inc = sv + add;
        off[tid] = inc;
        int st = inc - v;
        cur[tid] = st;
        soff[b * BKT_NODES + tid] = (unsigned short)st;
        scnt[b * BKT_NODES + tid] = (unsigned short)v;
    }
    __syncthreads();
    for (int i = tid; i < n; i += 512) {
        unsigned u = stage[i];
        int pos = atomicAdd(&cur[u & (BKT_NODES - 1)], 1);
        eSrc[pos] = u >> BKT_SHIFT;
    }
    __syncthreads();

    // persist sorted src list for k_agg2
    for (int i = tid; i < n; i += 512) gbuf[(size_t)b * BSTRIDE + i] = eSrc[i];

    int node = tid >> 2;
    int q = (tid & 3) * 4;
    int gnode = (b << BKT_SHIFT) + node;
    int end = off[node];
    int start = end - cnt[node];

    // self row + 4-deep unrolled gather: maximize outstanding loads per lane
    float4 bq = {0.f, 0.f, 0.f, 0.f};
    if (gnode < NN) bq = *(const float4*)(A + (size_t)gnode * NH + q);
    float4 a0 = {0.f, 0.f, 0.f, 0.f}, a1 = {0.f, 0.f, 0.f, 0.f};
    float4 a2 = {0.f, 0.f, 0.f, 0.f}, a3 = {0.f, 0.f, 0.f, 0.f};
    int j = start;
    for (; j + 4 <= end; j += 4) {
        int e0 = eSrc[j];
        int e1 = eSrc[j + 1];
        int e2 = eSrc[j + 2];
        int e3 = eSrc[j + 3];
        float4 v0 = *(const float4*)(A + (size_t)e0 * NH + q);
        float4 v1 = *(const float4*)(A + (size_t)e1 * NH + q);
        float4 v2 = *(const float4*)(A + (size_t)e2 * NH + q);
        float4 v3 = *(const float4*)(A + (size_t)e3 * NH + q);
        a0.x += v0.x; a0.y += v0.y; a0.z += v0.z; a0.w += v0.w;
        a1.x += v1.x; a1.y += v1.y; a1.z += v1.z; a1.w += v1.w;
        a2.x += v2.x; a2.y += v2.y; a2.z += v2.z; a2.w += v2.w;
        a3.x += v3.x; a3.y += v3.y; a3.z += v3.z; a3.w += v3.w;
    }
    for (; j < end; ++j) {
        int e0 = eSrc[j];
        float4 v0 = *(const float4*)(A + (size_t)e0 * NH + q);
        a0.x += v0.x; a0.y += v0.y; a0.z += v0.z; a0.w += v0.w;
    }
    a0.x += a2.x; a0.y += a2.y; a0.z += a2.z; a0.w += a2.w;
    a1.x += a3.x; a1.y += a3.y; a1.z += a3.z; a1.w += a3.w;
    Bl[node * 17 + q + 0] = fmaxf(bq.x + bb1[q + 0] + a0.x + a1.x, 0.f);
    Bl[node * 17 + q + 1] = fmaxf(bq.y + bb1[q + 1] + a0.y + a1.y, 0.f);
    Bl[node * 17 + q + 2] = fmaxf(bq.z + bb1[q + 2] + a0.z + a1.z, 0.f);
    Bl[node * 17 + q + 3] = fmaxf(bq.w + bb1[q + 3] + a0.w + a1.w, 0.f);
    __syncthreads();

    // t = relu(h@W2+b2)
    float t0 = bb2[q], t1 = bb2[q + 1], t2 = bb2[q + 2], t3 = bb2[q + 3];
#pragma unroll
    for (int k = 0; k < NH; ++k) {
        float hk = Bl[node * 17 + k];
        t0 += hk * w2[k * NH + q + 0];
        t1 += hk * w2[k * NH + q + 1];
        t2 += hk * w2[k * NH + q + 2];
        t3 += hk * w2[k * NH + q + 3];
    }
    Tl[node * 17 + q + 0] = fmaxf(t0, 0.f);
    Tl[node * 17 + q + 1] = fmaxf(t1, 0.f);
    Tl[node * 17 + q + 2] = fmaxf(t2, 0.f);
    Tl[node * 17 + q + 3] = fmaxf(t3, 0.f);
    __syncthreads();

    // z = t@W3 ; A2 = z  (b3 folded into agg2's self-term)
    float z0 = 0.f, z1 = 0.f, z2 = 0.f, z3 = 0.f;
#pragma unroll
    for (int k = 0; k < NH; ++k) {
        float tk = Tl[node * 17 + k];
        z0 += tk * w3[k * NH + q + 0];
        z1 += tk * w3[k * NH + q + 1];
        z2 += tk * w3[k * NH + q + 2];
        z3 += tk * w3[k * NH + q + 3];
    }
    if (gnode < NN) {
        float4 az = {z0, z1, z2, z3};
        *(float4*)(A2 + (size_t)gnode * NH + q) = az;
    }
}

// ------- k_agg2: NO sort (persisted list); unroll-4 gather; fused head. -------
__global__ __launch_bounds__(512) void k_agg2(
    const float* __restrict__ A2,
    const int* __restrict__ tcnt, const unsigned* __restrict__ gbuf,
    const unsigned short* __restrict__ soff, const unsigned short* __restrict__ scnt,
    const float* __restrict__ b3,
    const float* __restrict__ W4, const float* __restrict__ b4,
    float* __restrict__ out) {
    __shared__ unsigned eSrc[BSTRIDE];
    __shared__ int off[BKT_NODES], cnt[BKT_NODES];
    __shared__ float Bl[BKT_NODES * 17];
    __shared__ float w4[NH * NC];
    __shared__ float bb3[NH];
    __shared__ float bb4[NC];

    int b = blockIdx.x;
    int tid = threadIdx.x;
    for (int i = tid; i < NH * NC; i += 512) w4[i] = W4[i];
    if (tid < NH) bb3[tid] = b3[tid];
    if (tid < NC) bb4[tid] = b4[tid];
    int n = tcnt[b];
    if (n > BSTRIDE) n = BSTRIDE;
    if (tid < BKT_NODES) {
        off[tid] = soff[b * BKT_NODES + tid];
        cnt[tid] = scnt[b * BKT_NODES + tid];
    }
    for (int i = tid; i < n; i += 512) eSrc[i] = gbuf[(size_t)b * BSTRIDE + i];
    __syncthreads();

    int node = tid >> 2;
    int q = (tid & 3) * 4;
    int gnode = (b << BKT_SHIFT) + node;
    int start = off[node];
    int end = start + cnt[node];

    float4 bq = {0.f, 0.f, 0.f, 0.f};
    if (gnode < NN) bq = *(const float4*)(A2 + (size_t)gnode * NH + q);
    float4 a0 = {0.f, 0.f, 0.f, 0.f}, a1 = {0.f, 0.f, 0.f, 0.f};
    float4 a2 = {0.f, 0.f, 0.f, 0.f}, a3 = {0.f, 0.f, 0.f, 0.f};
    int j = start;
    for (; j + 4 <= end; j += 4) {
        int e0 = eSrc[j];
        int e1 = eSrc[j + 1];
        int e2 = eSrc[j + 2];
        int e3 = eSrc[j + 3];
        float4 v0 = *(const float4*)(A2 + (size_t)e0 * NH + q);
        float4 v1 = *(const float4*)(A2 + (size_t)e1 * NH + q);
        float4 v2 = *(const float4*)(A2 + (size_t)e2 * NH + q);
        float4 v3 = *(const float4*)(A2 + (size_t)e3 * NH + q);
        a0.x += v0.x; a0.y += v0.y; a0.z += v0.z; a0.w += v0.w;
        a1.x += v1.x; a1.y += v1.y; a1.z += v1.z; a1.w += v1.w;
        a2.x += v2.x; a2.y += v2.y; a2.z += v2.z; a2.w += v2.w;
        a3.x += v3.x; a3.y += v3.y; a3.z += v3.z; a3.w += v3.w;
    }
    for (; j < end; ++j) {
        int e0 = eSrc[j];
        float4 v0 = *(const float4*)(A2 + (size_t)e0 * NH + q);
        a0.x += v0.x; a0.y += v0.y; a0.z += v0.z; a0.w += v0.w;
    }
    a0.x += a2.x; a0.y += a2.y; a0.z += a2.z; a0.w += a2.w;
    a1.x += a3.x; a1.y += a3.y; a1.z += a3.z; a1.w += a3.w;
    Bl[node * 17 + q + 0] = fmaxf(bq.x + bb3[q + 0] + a0.x + a1.x, 0.f);
    Bl[node * 17 + q + 1] = fmaxf(bq.y + bb3[q + 1] + a0.y + a1.y, 0.f);
    Bl[node * 17 + q + 2] = fmaxf(bq.z + bb3[q + 2] + a0.z + a1.z, 0.f);
    Bl[node * 17 + q + 3] = fmaxf(bq.w + bb3[q + 3] + a0.w + a1.w, 0.f);
    __syncthreads();

    // head: one thread per node
    if (tid < BKT_NODES) {
        int nd = tid;
        int gn = (b << BKT_SHIFT) + nd;
        if (gn < NN) {
            float o[NC];
#pragma unroll
            for (int c = 0; c < NC; ++c) o[c] = bb4[c];
#pragma unroll
            for (int k = 0; k < NH; ++k) {
                float hk = Bl[nd * 17 + k];
#pragma unroll
                for (int c = 0; c < NC; ++c) o[c] += hk * w4[k * NC + c];
            }
            float m = o[0];
#pragma unroll
            for (int c = 1; c < NC; ++c) m = fmaxf(m, o[c]);
            float s = 0.f;
#pragma unroll
            for (int c = 0; c < NC; ++c) s += expf(o[c] - m);
            float ls = m + logf(s);
            float* op = out + (size_t)gn * NC;
#pragma unroll
            for (int c = 0; c < NC; ++c) op[c] = o[c] - ls;
        }
    }
}

extern "C" void kernel_launch(void* const* d_in, const int* in_sizes, int n_in,
                              void* d_out, int out_size, void* d_ws, size_t ws_size,
                              hipStream_t stream) {
    const float* x  = (const float*)d_in[0];
    const int*   ei = (const int*)d_in[1];   // [2, NE] flat: src then dst
    const float* W1 = (const float*)d_in[2];
    const float* b1 = (const float*)d_in[3];
    const float* W2 = (const float*)d_in[4];
    const float* b2 = (const float*)d_in[5];
    const float* W3 = (const float*)d_in[6];
    const float* b3 = (const float*)d_in[7];
    const float* W4 = (const float*)d_in[8];
    const float* b4 = (const float*)d_in[9];
    float* out = (float*)d_out;

    const int* src = ei;
    const int* dst = ei + NE;

    // workspace layout
    float*          A    = (float*)d_ws;                           // 6.4 MB
    float*          A2   = A + (size_t)NN * NH;                    // 6.4 MB
    unsigned*       gbuf = (unsigned*)(A2 + (size_t)NN * NH);      // 6.4 MB
    int*            gcnt = (int*)(gbuf + (size_t)NBUCKET * BSTRIDE);   // 1 MB
    int*            gbase= gcnt + (size_t)NBUCKET * NBLK_PAD;      // 1 MB
    int*            tcnt = gbase + (size_t)NBUCKET * NBLK_PAD;     // 3 KB
    unsigned short* soff = (unsigned short*)(tcnt + ((NBUCKET + 3) & ~3)); // 200 KB
    unsigned short* scnt = soff + (size_t)NBUCKET * BKT_NODES;     // 200 KB

    k1_fused<<<NODE_BLOCKS + NBLK_COUNT, 256, 0, stream>>>(x, W1, A, dst, gcnt);
    k_base<<<NBUCKET, 320, 0, stream>>>(gcnt, gbase, tcnt);
    k_scatter<<<NBLK_BUCKET, 1024, 0, stream>>>(src, dst, gbase, gbuf);
    k_agg1<<<NBUCKET, 512, 0, stream>>>(A, A2, tcnt, gbuf, soff, scnt, b1, W2, b2, W3);
    k_agg2<<<NBUCKET, 512, 0, stream>>>(A2, tcnt, gbuf, soff, scnt, b3, W4, b4, out);
}